// Round 2
// baseline (360.118 us; speedup 1.0000x reference)
//
#include <hip/hip_runtime.h>
#include <stdint.h>

// KMaxPool: rows of S=4096 f32, top-K=8 values, output in original index order.
// One wave per row; row lives in VGPRs (16 x float4/lane), single HBM pass.
//
// R2 changes vs R1 (theory: R1 was VGPR-spill / serial-shuffle-latency bound, ~110us):
//  - __launch_bounds__(256,3): 170-VGPR cap, spill impossible (est. ~105 live).
//  - threshold via 6-round butterfly top-8 merge (48 shuffles in 6 latency
//    windows, exact 8th-of-512-submaxes) instead of 48 dependent shuffles.
//  - final selection via packed-u64 keys + LDS broadcast insertion (0 shuffles)
//    instead of 96 dependent shuffles. Key = (ordered(val)<<32)|(4095-idx):
//    key desc == (value desc, index asc) == JAX top_k tie semantics.
#define WPB    4
#define CAP    256
#define KK     8
#define SLEN   4096
#define CHUNKS 16

__global__ __launch_bounds__(256, 3)
void kmax_kernel(const float* __restrict__ x, float* __restrict__ out, int nrows) {
    const int wave = threadIdx.x >> 6;
    const int lane = threadIdx.x & 63;
    const int row  = blockIdx.x * WPB + wave;
    const bool active = row < nrows;

    __shared__ int s_cnt[WPB];
    __shared__ unsigned long long s_key[WPB][CAP];

    if (lane == 0) s_cnt[wave] = 0;
    __syncthreads();

    const float NEG_INF = __int_as_float(0xff800000);
    float Tthr = 0.0f;

    if (active) {
        const float4* xr = reinterpret_cast<const float4*>(x + (size_t)row * SLEN);
        float4 f[CHUNKS];
        #pragma unroll
        for (int j = 0; j < CHUNKS; ++j)
            f[j] = xr[j * 64 + lane];

        // 8 substream running maxes per lane (512 disjoint groups of 8 elements)
        float m[8];
        #pragma unroll
        for (int e = 0; e < 8; ++e) m[e] = NEG_INF;
        #pragma unroll
        for (int j = 0; j < CHUNKS; ++j) {
            const int b = (j & 1) * 4;
            m[b + 0] = fmaxf(m[b + 0], f[j].x);
            m[b + 1] = fmaxf(m[b + 1], f[j].y);
            m[b + 2] = fmaxf(m[b + 2], f[j].z);
            m[b + 3] = fmaxf(m[b + 3], f[j].w);
        }

        // sort m[0..7] descending (Batcher, 19 CAS)
        #define MCAS(a, b) { float hi = fmaxf(m[a], m[b]); float lo = fminf(m[a], m[b]); m[a] = hi; m[b] = lo; }
        MCAS(0,1) MCAS(2,3) MCAS(4,5) MCAS(6,7)
        MCAS(0,2) MCAS(1,3) MCAS(4,6) MCAS(5,7)
        MCAS(1,2) MCAS(5,6)
        MCAS(0,4) MCAS(1,5) MCAS(2,6) MCAS(3,7)
        MCAS(2,4) MCAS(3,5)
        MCAS(1,2) MCAS(3,4) MCAS(5,6)
        #undef MCAS

        // butterfly top-8 merge across 64 lanes: 6 rounds, each lane ends with
        // the exact sorted top-8 of all 512 substream maxes. t[i]=max(a[i],b[7-i])
        // is the top-8 multiset (bitonic), then 3-stage bitonic resort.
        #pragma unroll
        for (int s = 1; s < 64; s <<= 1) {
            float b[8], t[8];
            #pragma unroll
            for (int i = 0; i < 8; ++i) b[i] = __shfl_xor(m[i], s, 64);
            #pragma unroll
            for (int i = 0; i < 8; ++i) t[i] = fmaxf(m[i], b[7 - i]);
            #define BCAS(a, c) { float hi = fmaxf(t[a], t[c]); float lo = fminf(t[a], t[c]); t[a] = hi; t[c] = lo; }
            BCAS(0,4) BCAS(1,5) BCAS(2,6) BCAS(3,7)
            BCAS(0,2) BCAS(1,3) BCAS(4,6) BCAS(5,7)
            BCAS(0,1) BCAS(2,3) BCAS(4,5) BCAS(6,7)
            #undef BCAS
            #pragma unroll
            for (int i = 0; i < 8; ++i) m[i] = t[i];
        }
        Tthr = m[7];   // exact 8th-largest substream max: >=8 row elements >= Tthr,
                       // and Tthr <= true 8th-largest => candidates superset of top-8

        // rescan registers; pack qualifying (val, idx) into u64 keys in LDS
        #pragma unroll
        for (int j = 0; j < CHUNKS; ++j) {
            const float4 v = f[j];
            const bool p0 = v.x >= Tthr, p1 = v.y >= Tthr, p2 = v.z >= Tthr, p3 = v.w >= Tthr;
            if (p0 || p1 || p2 || p3) {
                const int base = (j * 64 + lane) * 4;
                #define PUSH(val, idx) { \
                    int p = atomicAdd(&s_cnt[wave], 1); \
                    if (p < CAP) { \
                        unsigned u = __float_as_uint(val); \
                        u ^= ((unsigned)((int)u >> 31)) | 0x80000000u; \
                        s_key[wave][p] = ((unsigned long long)u << 32) | (unsigned)(4095 - (idx)); \
                    } }
                if (p0) PUSH(v.x, base + 0)
                if (p1) PUSH(v.y, base + 1)
                if (p2) PUSH(v.z, base + 2)
                if (p3) PUSH(v.w, base + 3)
                #undef PUSH
            }
        }
    }

    __syncthreads();

    if (active) {
        int n = s_cnt[wave];
        if (n > CAP) n = CAP;

        // all 64 lanes redundantly insertion-select top-8 keys from the LDS
        // list (broadcast reads, no shuffles, wave-uniform control flow)
        unsigned long long kk[KK];
        #pragma unroll
        for (int i = 0; i < KK; ++i) kk[i] = 0ull;
        for (int i = 0; i < n; ++i) {
            unsigned long long c = s_key[wave][i];
            if (c > kk[7]) {
                #pragma unroll
                for (int t = 7; t > 0; --t)
                    kk[t] = (c > kk[t - 1]) ? kk[t - 1] : ((c > kk[t]) ? c : kk[t]);
                kk[0] = (c > kk[0]) ? c : kk[0];
            }
        }

        // reorder the 8 winners by ascending original index == descending low32
        #define ICAS(a, b) { bool sw = (unsigned)kk[a] < (unsigned)kk[b]; \
            unsigned long long hi = sw ? kk[b] : kk[a]; \
            unsigned long long lo = sw ? kk[a] : kk[b]; \
            kk[a] = hi; kk[b] = lo; }
        ICAS(0,1) ICAS(2,3) ICAS(4,5) ICAS(6,7)
        ICAS(0,2) ICAS(1,3) ICAS(4,6) ICAS(5,7)
        ICAS(1,2) ICAS(5,6)
        ICAS(0,4) ICAS(1,5) ICAS(2,6) ICAS(3,7)
        ICAS(2,4) ICAS(3,5)
        ICAS(1,2) ICAS(3,4) ICAS(5,6)
        #undef ICAS

        if (lane == 0) {
            float vals[KK];
            #pragma unroll
            for (int i = 0; i < KK; ++i) {
                unsigned g = (unsigned)(kk[i] >> 32);
                unsigned msk = ((int)g < 0) ? 0x80000000u : 0xFFFFFFFFu;
                vals[i] = __uint_as_float(g ^ msk);
            }
            float4* o = reinterpret_cast<float4*>(out + (size_t)row * KK);
            o[0] = make_float4(vals[0], vals[1], vals[2], vals[3]);
            o[1] = make_float4(vals[4], vals[5], vals[6], vals[7]);
        }
    }
}

extern "C" void kernel_launch(void* const* d_in, const int* in_sizes, int n_in,
                              void* d_out, int out_size, void* d_ws, size_t ws_size,
                              hipStream_t stream) {
    const float* x = (const float*)d_in[0];
    float* out = (float*)d_out;
    const int nrows = out_size / KK;                 // 16 * 1024 = 16384
    const int blocks = (nrows + WPB - 1) / WPB;      // 4096
    kmax_kernel<<<blocks, 256, 0, stream>>>(x, out, nrows);
}

// Round 3
// 355.769 us; speedup vs baseline: 1.0122x; 1.0122x over previous
//
#include <hip/hip_runtime.h>
#include <stdint.h>

// KMaxPool: rows of S=4096 f32, top-K=8 values, output in original index order.
// One wave per row.
//
// R3: row is staged HBM->LDS via global_load_lds (width 16) instead of being
// held in 64 VGPRs. R1/R2 timed identically despite different compute -> the
// invariant was the register-resident row, which forces the allocator to
// spill/rematerialize the rescan loads (row crosses HBM twice, ~113us). LDS
// staging makes the single HBM pass structural. All state is wave-private
// (own row, own candidate list) -> no __syncthreads anywhere.
#define WPB    4
#define CAP    128
#define KK     8
#define SLEN   4096
#define CHUNKS 16

typedef const __attribute__((address_space(1))) uint32_t g_u32;
typedef __attribute__((address_space(3))) uint32_t l_u32;

__global__ __launch_bounds__(256, 2)
void kmax_kernel(const float* __restrict__ x, float* __restrict__ out, int nrows) {
    const int wave = threadIdx.x >> 6;
    const int lane = threadIdx.x & 63;
    const int row  = blockIdx.x * WPB + wave;

    __shared__ float              s_row[WPB][SLEN];   // 64 KiB
    __shared__ int                s_cnt[WPB];
    __shared__ unsigned long long s_key[WPB][CAP];    // 4 KiB

    if (row >= nrows) return;          // no barriers in kernel -> safe

    if (lane == 0) s_cnt[wave] = 0;

    // ---- async DMA row -> LDS: 16 x (64 lanes x 16 B). LDS dst is
    // wave-uniform base; HW scatters lane i at base + i*16, matching the
    // contiguous row layout exactly.
    const float* gbase = x + (size_t)row * SLEN;
    float*       lbase = &s_row[wave][0];
    #pragma unroll
    for (int j = 0; j < CHUNKS; ++j) {
        __builtin_amdgcn_global_load_lds((g_u32*)(gbase + j * 256 + lane * 4),
                                         (l_u32*)(lbase + j * 256),
                                         16, 0, 0);
    }

    const float NEG_INF = __int_as_float(0xff800000);
    float m[8];
    #pragma unroll
    for (int e = 0; e < 8; ++e) m[e] = NEG_INF;

    const float4* lrow = reinterpret_cast<const float4*>(lbase);

    // ---- phase A: 8 substream running maxes per lane, pipelined in halves
    // against the in-flight DMA (vmcnt decrements in issue order).
    asm volatile("s_waitcnt vmcnt(8)" ::: "memory");
    #pragma unroll
    for (int j = 0; j < 8; ++j) {
        const float4 v = lrow[j * 64 + lane];
        const int b = (j & 1) * 4;
        m[b + 0] = fmaxf(m[b + 0], v.x);
        m[b + 1] = fmaxf(m[b + 1], v.y);
        m[b + 2] = fmaxf(m[b + 2], v.z);
        m[b + 3] = fmaxf(m[b + 3], v.w);
    }
    asm volatile("s_waitcnt vmcnt(0)" ::: "memory");
    #pragma unroll
    for (int j = 8; j < CHUNKS; ++j) {
        const float4 v = lrow[j * 64 + lane];
        const int b = (j & 1) * 4;
        m[b + 0] = fmaxf(m[b + 0], v.x);
        m[b + 1] = fmaxf(m[b + 1], v.y);
        m[b + 2] = fmaxf(m[b + 2], v.z);
        m[b + 3] = fmaxf(m[b + 3], v.w);
    }

    // ---- sort m[0..7] descending (Batcher, 19 CAS)
    #define MCAS(a, b) { float hi = fmaxf(m[a], m[b]); float lo = fminf(m[a], m[b]); m[a] = hi; m[b] = lo; }
    MCAS(0,1) MCAS(2,3) MCAS(4,5) MCAS(6,7)
    MCAS(0,2) MCAS(1,3) MCAS(4,6) MCAS(5,7)
    MCAS(1,2) MCAS(5,6)
    MCAS(0,4) MCAS(1,5) MCAS(2,6) MCAS(3,7)
    MCAS(2,4) MCAS(3,5)
    MCAS(1,2) MCAS(3,4) MCAS(5,6)
    #undef MCAS

    // ---- butterfly top-8 merge across 64 lanes (6 rounds) -> exact sorted
    // top-8 of the 512 substream maxes in every lane.
    #pragma unroll
    for (int s = 1; s < 64; s <<= 1) {
        float b[8], t[8];
        #pragma unroll
        for (int i = 0; i < 8; ++i) b[i] = __shfl_xor(m[i], s, 64);
        #pragma unroll
        for (int i = 0; i < 8; ++i) t[i] = fmaxf(m[i], b[7 - i]);
        #define BCAS(a, c) { float hi = fmaxf(t[a], t[c]); float lo = fminf(t[a], t[c]); t[a] = hi; t[c] = lo; }
        BCAS(0,4) BCAS(1,5) BCAS(2,6) BCAS(3,7)
        BCAS(0,2) BCAS(1,3) BCAS(4,6) BCAS(5,7)
        BCAS(0,1) BCAS(2,3) BCAS(4,5) BCAS(6,7)
        #undef BCAS
        #pragma unroll
        for (int i = 0; i < 8; ++i) m[i] = t[i];
    }
    const float Tthr = m[7];  // 8th-largest submax <= true 8th-largest element
                              // (submaxes are a subset of the row), and >=8
                              // elements >= Tthr -> candidate superset of top-8

    // ---- phase B: rescan row from LDS, push qualifying (val,idx) as packed
    // u64 keys: (ordered(val)<<32)|(4095-idx); key desc == (val desc, idx asc)
    // == JAX top_k tie semantics.
    #pragma unroll
    for (int j = 0; j < CHUNKS; ++j) {
        const float4 v = lrow[j * 64 + lane];
        const bool p0 = v.x >= Tthr, p1 = v.y >= Tthr, p2 = v.z >= Tthr, p3 = v.w >= Tthr;
        if (p0 || p1 || p2 || p3) {
            const int base = (j * 64 + lane) * 4;
            #define PUSH(val, idx) { \
                int p = atomicAdd(&s_cnt[wave], 1); \
                if (p < CAP) { \
                    unsigned u = __float_as_uint(val); \
                    u ^= ((unsigned)((int)u >> 31)) | 0x80000000u; \
                    s_key[wave][p] = ((unsigned long long)u << 32) | (unsigned)(4095 - (idx)); \
                } }
            if (p0) PUSH(v.x, base + 0)
            if (p1) PUSH(v.y, base + 1)
            if (p2) PUSH(v.z, base + 2)
            if (p3) PUSH(v.w, base + 3)
            #undef PUSH
        }
    }

    asm volatile("s_waitcnt lgkmcnt(0)" ::: "memory");   // wave-private: DS ops
                                                         // in order, just drain

    int n = s_cnt[wave];
    if (n > CAP) n = CAP;

    // ---- all lanes redundantly insertion-select top-8 keys (broadcast LDS
    // reads, wave-uniform control flow, zero shuffles)
    unsigned long long kk[KK];
    #pragma unroll
    for (int i = 0; i < KK; ++i) kk[i] = 0ull;
    for (int i = 0; i < n; ++i) {
        unsigned long long c = s_key[wave][i];
        if (c > kk[7]) {
            #pragma unroll
            for (int t = 7; t > 0; --t)
                kk[t] = (c > kk[t - 1]) ? kk[t - 1] : ((c > kk[t]) ? c : kk[t]);
            kk[0] = (c > kk[0]) ? c : kk[0];
        }
    }

    // ---- reorder winners by ascending original index == descending low32
    #define ICAS(a, b) { bool sw = (unsigned)kk[a] < (unsigned)kk[b]; \
        unsigned long long hi = sw ? kk[b] : kk[a]; \
        unsigned long long lo = sw ? kk[a] : kk[b]; \
        kk[a] = hi; kk[b] = lo; }
    ICAS(0,1) ICAS(2,3) ICAS(4,5) ICAS(6,7)
    ICAS(0,2) ICAS(1,3) ICAS(4,6) ICAS(5,7)
    ICAS(1,2) ICAS(5,6)
    ICAS(0,4) ICAS(1,5) ICAS(2,6) ICAS(3,7)
    ICAS(2,4) ICAS(3,5)
    ICAS(1,2) ICAS(3,4) ICAS(5,6)
    #undef ICAS

    if (lane == 0) {
        float vals[KK];
        #pragma unroll
        for (int i = 0; i < KK; ++i) {
            unsigned g = (unsigned)(kk[i] >> 32);
            unsigned msk = ((int)g < 0) ? 0x80000000u : 0xFFFFFFFFu;
            vals[i] = __uint_as_float(g ^ msk);
        }
        float4* o = reinterpret_cast<float4*>(out + (size_t)row * KK);
        o[0] = make_float4(vals[0], vals[1], vals[2], vals[3]);
        o[1] = make_float4(vals[4], vals[5], vals[6], vals[7]);
    }
}

extern "C" void kernel_launch(void* const* d_in, const int* in_sizes, int n_in,
                              void* d_out, int out_size, void* d_ws, size_t ws_size,
                              hipStream_t stream) {
    const float* x = (const float*)d_in[0];
    float* out = (float*)d_out;
    const int nrows = out_size / KK;                 // 16 * 1024 = 16384
    const int blocks = (nrows + WPB - 1) / WPB;      // 4096
    kmax_kernel<<<blocks, 256, 0, stream>>>(x, out, nrows);
}